// Round 1
// baseline (562.953 us; speedup 1.0000x reference)
//
#include <hip/hip_runtime.h>
#include <hip/hip_bf16.h>
#include <math.h>

// Problem constants (fixed by reference)
constexpr int T_ = 16384;
constexpr int D_ = 2048;   // hidden
constexpr int H_ = 1024;   // intermediate
constexpr int E_ = 8;

constexpr int BM = 128, BN = 128, BK = 64;
constexpr int MT_MAX = T_ / BM + E_;   // worst-case sum of per-expert ceil tiles = 136

typedef __bf16 bf16x8 __attribute__((ext_vector_type(8)));
typedef float  f32x4  __attribute__((ext_vector_type(4)));

__device__ __forceinline__ int imin(int a, int b) { return a < b ? a : b; }

// ---- LDS helpers: [rows][BK] bf16, row pitch 128B, XOR swizzle ((row&7)<<4) ----
__device__ __forceinline__ void st_lds8(char* lds, int row, int col, bf16x8 v) {
    int byte = row * (BK * 2) + ((col * 2) ^ ((row & 7) << 4));
    *reinterpret_cast<bf16x8*>(lds + byte) = v;
}
__device__ __forceinline__ bf16x8 ld_lds8(const char* lds, int row, int kbyte) {
    int byte = row * (BK * 2) + (kbyte ^ ((row & 7) << 4));
    return *reinterpret_cast<const bf16x8*>(lds + byte);
}

__device__ __forceinline__ bf16x8 cvt8(const float* p) {
    float4 u = *reinterpret_cast<const float4*>(p);
    float4 v = *reinterpret_cast<const float4*>(p + 4);
    bf16x8 r;
    r[0] = (__bf16)u.x; r[1] = (__bf16)u.y; r[2] = (__bf16)u.z; r[3] = (__bf16)u.w;
    r[4] = (__bf16)v.x; r[5] = (__bf16)v.y; r[6] = (__bf16)v.z; r[7] = (__bf16)v.w;
    return r;
}

// stage a 128x64 f32 tile -> bf16 LDS (256 threads, 4 chunks of 8 floats each)
template<bool CLAMP>
__device__ __forceinline__ void stage_f32(char* lds, const float* __restrict__ src,
                                          int ld, int valid, int tid) {
#pragma unroll
    for (int i = 0; i < 4; ++i) {
        int chunk = i * 256 + tid;       // 0..1023
        int row = chunk >> 3;            // 0..127
        int col = (chunk & 7) * 8;       // 0..56
        int r = CLAMP ? imin(row, valid - 1) : row;
        bf16x8 v = cvt8(src + (size_t)r * ld + col);
        st_lds8(lds, row, col, v);
    }
}

// stage a 128x64 bf16 tile -> LDS
__device__ __forceinline__ void stage_bf16(char* lds, const __bf16* __restrict__ src,
                                           int ld, int valid, int tid) {
#pragma unroll
    for (int i = 0; i < 4; ++i) {
        int chunk = i * 256 + tid;
        int row = chunk >> 3;
        int col = (chunk & 7) * 8;
        int r = imin(row, valid - 1);
        bf16x8 v = *reinterpret_cast<const bf16x8*>(src + (size_t)r * ld + col);
        st_lds8(lds, row, col, v);
    }
}

// uniform expert lookup: mt -> (e, row0, valid)
__device__ __forceinline__ bool find_expert(const int* __restrict__ counts, int mt,
                                            int& e, int& row0, int& valid) {
    int macc = 0, start = 0;
    e = -1;
    for (int i = 0; i < E_; ++i) {
        int c = counts[i];
        int t = (c + BM - 1) >> 7;
        if (e < 0 && mt < macc + t) {
            int lm = mt - macc;
            e = i; row0 = start + lm * BM; valid = imin(BM, c - lm * BM);
        }
        macc += t; start += c;
    }
    return e >= 0;
}

// ---------------- Stage 1: h = gelu_tanh(x@w1^T) * (x@w3^T), bf16 out ----------------
__global__ __launch_bounds__(256, 2) void ffn_stage1(
        const float* __restrict__ x, const float* __restrict__ w1,
        const float* __restrict__ w3, const int* __restrict__ counts,
        __bf16* __restrict__ hbuf) {
    __shared__ alignas(16) char sA [BM * BK * 2];
    __shared__ alignas(16) char sB1[BN * BK * 2];
    __shared__ alignas(16) char sB3[BN * BK * 2];

    int tid = threadIdx.x;
    int mt = blockIdx.x, nt = blockIdx.y;
    int e, row0, valid;
    if (!find_expert(counts, mt, e, row0, valid)) return;
    int ng0 = nt * BN;

    const float* Ab  = x  + (size_t)row0 * D_;
    const float* B1b = w1 + (size_t)e * H_ * D_ + (size_t)ng0 * D_;
    const float* B3b = w3 + (size_t)e * H_ * D_ + (size_t)ng0 * D_;

    f32x4 acc1[4][4] = {}; f32x4 acc3[4][4] = {};
    int wid = tid >> 6, lane = tid & 63;
    int wr = wid >> 1, wc = wid & 1;
    int frow = lane & 15, fkb = (lane >> 4) * 16;

    for (int k0 = 0; k0 < D_; k0 += BK) {
        stage_f32<true >(sA,  Ab  + k0, D_, valid, tid);
        stage_f32<false>(sB1, B1b + k0, D_, 0, tid);
        stage_f32<false>(sB3, B3b + k0, D_, 0, tid);
        __syncthreads();
#pragma unroll
        for (int kk = 0; kk < BK; kk += 32) {
            int kb = kk * 2 + fkb;
            bf16x8 a[4], b1[4], b3[4];
#pragma unroll
            for (int m = 0; m < 4; ++m) a[m]  = ld_lds8(sA,  wr * 64 + m * 16 + frow, kb);
#pragma unroll
            for (int n = 0; n < 4; ++n) { b1[n] = ld_lds8(sB1, wc * 64 + n * 16 + frow, kb);
                                          b3[n] = ld_lds8(sB3, wc * 64 + n * 16 + frow, kb); }
#pragma unroll
            for (int m = 0; m < 4; ++m)
#pragma unroll
                for (int n = 0; n < 4; ++n) {
                    acc1[m][n] = __builtin_amdgcn_mfma_f32_16x16x32_bf16(a[m], b1[n], acc1[m][n], 0, 0, 0);
                    acc3[m][n] = __builtin_amdgcn_mfma_f32_16x16x32_bf16(a[m], b3[n], acc3[m][n], 0, 0, 0);
                }
        }
        __syncthreads();
    }

    // epilogue: gelu_tanh(c1) * c3 -> bf16
#pragma unroll
    for (int m = 0; m < 4; ++m) {
#pragma unroll
        for (int j = 0; j < 4; ++j) {
            int lrow = wr * 64 + m * 16 + (lane >> 4) * 4 + j;
            if (lrow < valid) {
                size_t gro = (size_t)(row0 + lrow) * H_;
#pragma unroll
                for (int n = 0; n < 4; ++n) {
                    float c1 = acc1[m][n][j], c3 = acc3[m][n][j];
                    float inner = 0.7978845608028654f * (c1 + 0.044715f * c1 * c1 * c1);
                    float g = 0.5f * c1 * (1.0f + tanhf(inner));
                    int col = ng0 + wc * 64 + n * 16 + (lane & 15);
                    hbuf[gro + col] = (__bf16)(g * c3);
                }
            }
        }
    }
}

// ---------------- Stage 2: out = h @ w2^T (f32 out) ----------------
__global__ __launch_bounds__(256, 2) void ffn_stage2(
        const __bf16* __restrict__ hbuf, const float* __restrict__ w2,
        const int* __restrict__ counts, float* __restrict__ out) {
    __shared__ alignas(16) char sA[BM * BK * 2];
    __shared__ alignas(16) char sB[BN * BK * 2];

    int tid = threadIdx.x;
    int mt = blockIdx.x, nt = blockIdx.y;
    int e, row0, valid;
    if (!find_expert(counts, mt, e, row0, valid)) return;
    int ng0 = nt * BN;   // over D_ = 2048

    const __bf16* Ab = hbuf + (size_t)row0 * H_;
    const float*  Bb = w2 + (size_t)e * D_ * H_ + (size_t)ng0 * H_;

    f32x4 acc[4][4] = {};
    int wid = tid >> 6, lane = tid & 63;
    int wr = wid >> 1, wc = wid & 1;
    int frow = lane & 15, fkb = (lane >> 4) * 16;

    for (int k0 = 0; k0 < H_; k0 += BK) {
        stage_bf16(sA, Ab + k0, H_, valid, tid);
        stage_f32<false>(sB, Bb + k0, H_, 0, tid);
        __syncthreads();
#pragma unroll
        for (int kk = 0; kk < BK; kk += 32) {
            int kb = kk * 2 + fkb;
            bf16x8 a[4], b[4];
#pragma unroll
            for (int m = 0; m < 4; ++m) a[m] = ld_lds8(sA, wr * 64 + m * 16 + frow, kb);
#pragma unroll
            for (int n = 0; n < 4; ++n) b[n] = ld_lds8(sB, wc * 64 + n * 16 + frow, kb);
#pragma unroll
            for (int m = 0; m < 4; ++m)
#pragma unroll
                for (int n = 0; n < 4; ++n)
                    acc[m][n] = __builtin_amdgcn_mfma_f32_16x16x32_bf16(a[m], b[n], acc[m][n], 0, 0, 0);
        }
        __syncthreads();
    }

#pragma unroll
    for (int m = 0; m < 4; ++m) {
#pragma unroll
        for (int j = 0; j < 4; ++j) {
            int lrow = wr * 64 + m * 16 + (lane >> 4) * 4 + j;
            if (lrow < valid) {
                size_t gro = (size_t)(row0 + lrow) * D_;
#pragma unroll
                for (int n = 0; n < 4; ++n) {
                    int col = ng0 + wc * 64 + n * 16 + (lane & 15);
                    out[gro + col] = acc[m][n][j];
                }
            }
        }
    }
}

extern "C" void kernel_launch(void* const* d_in, const int* in_sizes, int n_in,
                              void* d_out, int out_size, void* d_ws, size_t ws_size,
                              hipStream_t stream) {
    const float* x      = (const float*)d_in[0];
    const float* w1     = (const float*)d_in[1];
    const float* w2     = (const float*)d_in[2];
    const float* w3     = (const float*)d_in[3];
    const int*   counts = (const int*)d_in[4];
    float* out = (float*)d_out;
    __bf16* hbuf = (__bf16*)d_ws;   // T_ * H_ bf16 = 33.5 MB

    dim3 g1(MT_MAX, H_ / BN);   // 136 x 8
    dim3 g2(MT_MAX, D_ / BN);   // 136 x 16
    ffn_stage1<<<g1, 256, 0, stream>>>(x, w1, w3, counts, hbuf);
    ffn_stage2<<<g2, 256, 0, stream>>>(hbuf, w2, counts, out);
}

// Round 2
// 390.513 us; speedup vs baseline: 1.4416x; 1.4416x over previous
//
#include <hip/hip_runtime.h>
#include <hip/hip_bf16.h>
#include <math.h>

// Problem constants (fixed by reference)
constexpr int T_ = 16384;
constexpr int D_ = 2048;   // hidden
constexpr int H_ = 1024;   // intermediate
constexpr int E_ = 8;

constexpr int BM = 128, BN = 128, BK = 64;
constexpr int MT_MAX = T_ / BM + E_;   // worst-case sum of per-expert ceil tiles = 136

typedef __bf16 bf16x8 __attribute__((ext_vector_type(8)));
typedef float  f32x4  __attribute__((ext_vector_type(4)));

__device__ __forceinline__ int imin(int a, int b) { return a < b ? a : b; }

// ---- LDS helpers: [rows][BK] bf16, row pitch 128B, XOR swizzle ((row&7)<<4) ----
__device__ __forceinline__ void st_lds8(char* lds, int row, int col, bf16x8 v) {
    int byte = row * (BK * 2) + ((col * 2) ^ ((row & 7) << 4));
    *reinterpret_cast<bf16x8*>(lds + byte) = v;
}
__device__ __forceinline__ bf16x8 ld_lds8(const char* lds, int row, int kbyte) {
    int byte = row * (BK * 2) + (kbyte ^ ((row & 7) << 4));
    return *reinterpret_cast<const bf16x8*>(lds + byte);
}

__device__ __forceinline__ bf16x8 cvt8(const float* p) {
    float4 u = *reinterpret_cast<const float4*>(p);
    float4 v = *reinterpret_cast<const float4*>(p + 4);
    bf16x8 r;
    r[0] = (__bf16)u.x; r[1] = (__bf16)u.y; r[2] = (__bf16)u.z; r[3] = (__bf16)u.w;
    r[4] = (__bf16)v.x; r[5] = (__bf16)v.y; r[6] = (__bf16)v.z; r[7] = (__bf16)v.w;
    return r;
}

// stage a 128x64 f32 tile -> bf16 LDS (256 threads) [fallback path]
template<bool CLAMP>
__device__ __forceinline__ void stage_f32(char* lds, const float* __restrict__ src,
                                          int ld, int valid, int tid) {
#pragma unroll
    for (int i = 0; i < 4; ++i) {
        int chunk = i * 256 + tid;
        int row = chunk >> 3;
        int col = (chunk & 7) * 8;
        int r = CLAMP ? imin(row, valid - 1) : row;
        bf16x8 v = cvt8(src + (size_t)r * ld + col);
        st_lds8(lds, row, col, v);
    }
}

// stage a 128x64 bf16 tile -> LDS via reg [fallback path]
__device__ __forceinline__ void stage_bf16(char* lds, const __bf16* __restrict__ src,
                                           int ld, int valid, int tid) {
#pragma unroll
    for (int i = 0; i < 4; ++i) {
        int chunk = i * 256 + tid;
        int row = chunk >> 3;
        int col = (chunk & 7) * 8;
        int r = imin(row, valid - 1);
        bf16x8 v = *reinterpret_cast<const bf16x8*>(src + (size_t)r * ld + col);
        st_lds8(lds, row, col, v);
    }
}

// stage a 128x64 bf16 tile -> LDS via global_load_lds (16B), source pre-swizzled
// so LDS layout matches ld_lds8's XOR pattern. 4 waves, wave w -> chunks [4w,4w+4).
__device__ __forceinline__ void stage_glds(char* lds, const __bf16* __restrict__ src,
                                           int ld, int valid, int tid) {
    int wave = tid >> 6, l = tid & 63;
#pragma unroll
    for (int i = 0; i < 4; ++i) {
        int chunk = wave * 4 + i;            // 0..15, 1KB each
        int row = chunk * 8 + (l >> 3);      // LDS dest row (lane-implicit)
        int rc = imin(row, valid - 1);       // clamp source row for partial tiles
        int colb = ((l & 7) * 16) ^ ((row & 7) << 4);   // pre-swizzled source col
        const char* gp = reinterpret_cast<const char*>(src)
                       + (size_t)rc * ((size_t)ld * 2) + colb;
        __builtin_amdgcn_global_load_lds(
            (const __attribute__((address_space(1))) void*)gp,
            (__attribute__((address_space(3))) void*)(lds + chunk * 1024), 16, 0, 0);
    }
}

// uniform expert lookup: mt -> (e, row0, valid)
__device__ __forceinline__ bool find_expert(const int* __restrict__ counts, int mt,
                                            int& e, int& row0, int& valid) {
    int macc = 0, start = 0;
    e = -1;
    for (int i = 0; i < E_; ++i) {
        int c = counts[i];
        int t = (c + BM - 1) >> 7;
        if (e < 0 && mt < macc + t) {
            int lm = mt - macc;
            e = i; row0 = start + lm * BM; valid = imin(BM, c - lm * BM);
        }
        macc += t; start += c;
    }
    return e >= 0;
}

// ---------------- f32 -> bf16 bulk conversion ----------------
__global__ __launch_bounds__(256) void cvt_f32_bf16(const float* __restrict__ in,
                                                    __bf16* __restrict__ out, int n8) {
    int i = blockIdx.x * blockDim.x + threadIdx.x;
    int stride = gridDim.x * blockDim.x;
    for (; i < n8; i += stride) {
        bf16x8 v = cvt8(in + (size_t)i * 8);
        *reinterpret_cast<bf16x8*>(out + (size_t)i * 8) = v;
    }
}

// ================= Path A: all-bf16 GEMMs with global_load_lds =================

__global__ __launch_bounds__(256, 2) void ffn_stage1_glds(
        const __bf16* __restrict__ xb, const __bf16* __restrict__ w1b,
        const __bf16* __restrict__ w3b, const int* __restrict__ counts,
        __bf16* __restrict__ hbuf) {
    __shared__ alignas(16) char sA [BM * BK * 2];
    __shared__ alignas(16) char sB1[BN * BK * 2];
    __shared__ alignas(16) char sB3[BN * BK * 2];

    int tid = threadIdx.x;
    int mt = blockIdx.x, nt = blockIdx.y;
    int e, row0, valid;
    if (!find_expert(counts, mt, e, row0, valid)) return;
    int ng0 = nt * BN;

    const __bf16* Ab  = xb  + (size_t)row0 * D_;
    const __bf16* B1b = w1b + (size_t)e * H_ * D_ + (size_t)ng0 * D_;
    const __bf16* B3b = w3b + (size_t)e * H_ * D_ + (size_t)ng0 * D_;

    f32x4 acc1[4][4] = {}; f32x4 acc3[4][4] = {};
    int wid = tid >> 6, lane = tid & 63;
    int wr = wid >> 1, wc = wid & 1;
    int frow = lane & 15, fkb = (lane >> 4) * 16;

    for (int k0 = 0; k0 < D_; k0 += BK) {
        stage_glds(sA,  Ab  + k0, D_, valid, tid);
        stage_glds(sB1, B1b + k0, D_, BM, tid);
        stage_glds(sB3, B3b + k0, D_, BM, tid);
        __syncthreads();
#pragma unroll
        for (int kk = 0; kk < BK; kk += 32) {
            int kb = kk * 2 + fkb;
            bf16x8 a[4], b1[4], b3[4];
#pragma unroll
            for (int m = 0; m < 4; ++m) a[m]  = ld_lds8(sA,  wr * 64 + m * 16 + frow, kb);
#pragma unroll
            for (int n = 0; n < 4; ++n) { b1[n] = ld_lds8(sB1, wc * 64 + n * 16 + frow, kb);
                                          b3[n] = ld_lds8(sB3, wc * 64 + n * 16 + frow, kb); }
#pragma unroll
            for (int m = 0; m < 4; ++m)
#pragma unroll
                for (int n = 0; n < 4; ++n) {
                    acc1[m][n] = __builtin_amdgcn_mfma_f32_16x16x32_bf16(a[m], b1[n], acc1[m][n], 0, 0, 0);
                    acc3[m][n] = __builtin_amdgcn_mfma_f32_16x16x32_bf16(a[m], b3[n], acc3[m][n], 0, 0, 0);
                }
        }
        __syncthreads();
    }

#pragma unroll
    for (int m = 0; m < 4; ++m) {
#pragma unroll
        for (int j = 0; j < 4; ++j) {
            int lrow = wr * 64 + m * 16 + (lane >> 4) * 4 + j;
            if (lrow < valid) {
                size_t gro = (size_t)(row0 + lrow) * H_;
#pragma unroll
                for (int n = 0; n < 4; ++n) {
                    float c1 = acc1[m][n][j], c3 = acc3[m][n][j];
                    float inner = 0.7978845608028654f * (c1 + 0.044715f * c1 * c1 * c1);
                    float g = 0.5f * c1 * (1.0f + tanhf(inner));
                    int col = ng0 + wc * 64 + n * 16 + (lane & 15);
                    hbuf[gro + col] = (__bf16)(g * c3);
                }
            }
        }
    }
}

__global__ __launch_bounds__(256, 3) void ffn_stage2_glds(
        const __bf16* __restrict__ hbuf, const __bf16* __restrict__ w2b,
        const int* __restrict__ counts, float* __restrict__ out) {
    __shared__ alignas(16) char sA[BM * BK * 2];
    __shared__ alignas(16) char sB[BN * BK * 2];

    int tid = threadIdx.x;
    int mt = blockIdx.x, nt = blockIdx.y;
    int e, row0, valid;
    if (!find_expert(counts, mt, e, row0, valid)) return;
    int ng0 = nt * BN;

    const __bf16* Ab = hbuf + (size_t)row0 * H_;
    const __bf16* Bb = w2b + (size_t)e * D_ * H_ + (size_t)ng0 * H_;

    f32x4 acc[4][4] = {};
    int wid = tid >> 6, lane = tid & 63;
    int wr = wid >> 1, wc = wid & 1;
    int frow = lane & 15, fkb = (lane >> 4) * 16;

    for (int k0 = 0; k0 < H_; k0 += BK) {
        stage_glds(sA, Ab + k0, H_, valid, tid);
        stage_glds(sB, Bb + k0, H_, BM, tid);
        __syncthreads();
#pragma unroll
        for (int kk = 0; kk < BK; kk += 32) {
            int kb = kk * 2 + fkb;
            bf16x8 a[4], b[4];
#pragma unroll
            for (int m = 0; m < 4; ++m) a[m] = ld_lds8(sA, wr * 64 + m * 16 + frow, kb);
#pragma unroll
            for (int n = 0; n < 4; ++n) b[n] = ld_lds8(sB, wc * 64 + n * 16 + frow, kb);
#pragma unroll
            for (int m = 0; m < 4; ++m)
#pragma unroll
                for (int n = 0; n < 4; ++n)
                    acc[m][n] = __builtin_amdgcn_mfma_f32_16x16x32_bf16(a[m], b[n], acc[m][n], 0, 0, 0);
        }
        __syncthreads();
    }

#pragma unroll
    for (int m = 0; m < 4; ++m) {
#pragma unroll
        for (int j = 0; j < 4; ++j) {
            int lrow = wr * 64 + m * 16 + (lane >> 4) * 4 + j;
            if (lrow < valid) {
                size_t gro = (size_t)(row0 + lrow) * D_;
#pragma unroll
                for (int n = 0; n < 4; ++n) {
                    int col = ng0 + wc * 64 + n * 16 + (lane & 15);
                    out[gro + col] = acc[m][n][j];
                }
            }
        }
    }
}

// ================= Path B: round-1 fallback (reg-staged f32 convert) =================

__global__ __launch_bounds__(256, 2) void ffn_stage1(
        const float* __restrict__ x, const float* __restrict__ w1,
        const float* __restrict__ w3, const int* __restrict__ counts,
        __bf16* __restrict__ hbuf) {
    __shared__ alignas(16) char sA [BM * BK * 2];
    __shared__ alignas(16) char sB1[BN * BK * 2];
    __shared__ alignas(16) char sB3[BN * BK * 2];

    int tid = threadIdx.x;
    int mt = blockIdx.x, nt = blockIdx.y;
    int e, row0, valid;
    if (!find_expert(counts, mt, e, row0, valid)) return;
    int ng0 = nt * BN;

    const float* Ab  = x  + (size_t)row0 * D_;
    const float* B1b = w1 + (size_t)e * H_ * D_ + (size_t)ng0 * D_;
    const float* B3b = w3 + (size_t)e * H_ * D_ + (size_t)ng0 * D_;

    f32x4 acc1[4][4] = {}; f32x4 acc3[4][4] = {};
    int wid = tid >> 6, lane = tid & 63;
    int wr = wid >> 1, wc = wid & 1;
    int frow = lane & 15, fkb = (lane >> 4) * 16;

    for (int k0 = 0; k0 < D_; k0 += BK) {
        stage_f32<true >(sA,  Ab  + k0, D_, valid, tid);
        stage_f32<false>(sB1, B1b + k0, D_, 0, tid);
        stage_f32<false>(sB3, B3b + k0, D_, 0, tid);
        __syncthreads();
#pragma unroll
        for (int kk = 0; kk < BK; kk += 32) {
            int kb = kk * 2 + fkb;
            bf16x8 a[4], b1[4], b3[4];
#pragma unroll
            for (int m = 0; m < 4; ++m) a[m]  = ld_lds8(sA,  wr * 64 + m * 16 + frow, kb);
#pragma unroll
            for (int n = 0; n < 4; ++n) { b1[n] = ld_lds8(sB1, wc * 64 + n * 16 + frow, kb);
                                          b3[n] = ld_lds8(sB3, wc * 64 + n * 16 + frow, kb); }
#pragma unroll
            for (int m = 0; m < 4; ++m)
#pragma unroll
                for (int n = 0; n < 4; ++n) {
                    acc1[m][n] = __builtin_amdgcn_mfma_f32_16x16x32_bf16(a[m], b1[n], acc1[m][n], 0, 0, 0);
                    acc3[m][n] = __builtin_amdgcn_mfma_f32_16x16x32_bf16(a[m], b3[n], acc3[m][n], 0, 0, 0);
                }
        }
        __syncthreads();
    }

#pragma unroll
    for (int m = 0; m < 4; ++m) {
#pragma unroll
        for (int j = 0; j < 4; ++j) {
            int lrow = wr * 64 + m * 16 + (lane >> 4) * 4 + j;
            if (lrow < valid) {
                size_t gro = (size_t)(row0 + lrow) * H_;
#pragma unroll
                for (int n = 0; n < 4; ++n) {
                    float c1 = acc1[m][n][j], c3 = acc3[m][n][j];
                    float inner = 0.7978845608028654f * (c1 + 0.044715f * c1 * c1 * c1);
                    float g = 0.5f * c1 * (1.0f + tanhf(inner));
                    int col = ng0 + wc * 64 + n * 16 + (lane & 15);
                    hbuf[gro + col] = (__bf16)(g * c3);
                }
            }
        }
    }
}

__global__ __launch_bounds__(256, 2) void ffn_stage2(
        const __bf16* __restrict__ hbuf, const float* __restrict__ w2,
        const int* __restrict__ counts, float* __restrict__ out) {
    __shared__ alignas(16) char sA[BM * BK * 2];
    __shared__ alignas(16) char sB[BN * BK * 2];

    int tid = threadIdx.x;
    int mt = blockIdx.x, nt = blockIdx.y;
    int e, row0, valid;
    if (!find_expert(counts, mt, e, row0, valid)) return;
    int ng0 = nt * BN;

    const __bf16* Ab = hbuf + (size_t)row0 * H_;
    const float*  Bb = w2 + (size_t)e * D_ * H_ + (size_t)ng0 * H_;

    f32x4 acc[4][4] = {};
    int wid = tid >> 6, lane = tid & 63;
    int wr = wid >> 1, wc = wid & 1;
    int frow = lane & 15, fkb = (lane >> 4) * 16;

    for (int k0 = 0; k0 < H_; k0 += BK) {
        stage_bf16(sA, Ab + k0, H_, valid, tid);
        stage_f32<false>(sB, Bb + k0, H_, 0, tid);
        __syncthreads();
#pragma unroll
        for (int kk = 0; kk < BK; kk += 32) {
            int kb = kk * 2 + fkb;
            bf16x8 a[4], b[4];
#pragma unroll
            for (int m = 0; m < 4; ++m) a[m] = ld_lds8(sA, wr * 64 + m * 16 + frow, kb);
#pragma unroll
            for (int n = 0; n < 4; ++n) b[n] = ld_lds8(sB, wc * 64 + n * 16 + frow, kb);
#pragma unroll
            for (int m = 0; m < 4; ++m)
#pragma unroll
                for (int n = 0; n < 4; ++n)
                    acc[m][n] = __builtin_amdgcn_mfma_f32_16x16x32_bf16(a[m], b[n], acc[m][n], 0, 0, 0);
        }
        __syncthreads();
    }

#pragma unroll
    for (int m = 0; m < 4; ++m) {
#pragma unroll
        for (int j = 0; j < 4; ++j) {
            int lrow = wr * 64 + m * 16 + (lane >> 4) * 4 + j;
            if (lrow < valid) {
                size_t gro = (size_t)(row0 + lrow) * D_;
#pragma unroll
                for (int n = 0; n < 4; ++n) {
                    int col = ng0 + wc * 64 + n * 16 + (lane & 15);
                    out[gro + col] = acc[m][n][j];
                }
            }
        }
    }
}

extern "C" void kernel_launch(void* const* d_in, const int* in_sizes, int n_in,
                              void* d_out, int out_size, void* d_ws, size_t ws_size,
                              hipStream_t stream) {
    const float* x      = (const float*)d_in[0];
    const float* w1     = (const float*)d_in[1];
    const float* w2     = (const float*)d_in[2];
    const float* w3     = (const float*)d_in[3];
    const int*   counts = (const int*)d_in[4];
    float* out = (float*)d_out;

    const size_t XB = (size_t)T_ * D_ * 2;        // x bf16       67.1 MB
    const size_t HB = (size_t)T_ * H_ * 2;        // h bf16       33.6 MB
    const size_t WB = (size_t)E_ * H_ * D_ * 2;   // each weight  33.6 MB
    const size_t NEED = XB + HB + 3 * WB;         // 201.3 MB

    if (ws_size >= NEED) {
        char* ws = (char*)d_ws;
        __bf16* xb   = (__bf16*)(ws);
        __bf16* hbuf = (__bf16*)(ws + XB);
        __bf16* w1b  = (__bf16*)(ws + XB + HB);
        __bf16* w3b  = (__bf16*)(ws + XB + HB + WB);
        __bf16* w2b  = (__bf16*)(ws + XB + HB + 2 * WB);

        cvt_f32_bf16<<<2048, 256, 0, stream>>>(x,  xb,  T_ * D_ / 8);
        cvt_f32_bf16<<<2048, 256, 0, stream>>>(w1, w1b, E_ * H_ * D_ / 8);
        cvt_f32_bf16<<<2048, 256, 0, stream>>>(w3, w3b, E_ * H_ * D_ / 8);
        cvt_f32_bf16<<<2048, 256, 0, stream>>>(w2, w2b, E_ * D_ * H_ / 8);

        dim3 g1(MT_MAX, H_ / BN);   // 136 x 8
        dim3 g2(MT_MAX, D_ / BN);   // 136 x 16
        ffn_stage1_glds<<<g1, 256, 0, stream>>>(xb, w1b, w3b, counts, hbuf);
        ffn_stage2_glds<<<g2, 256, 0, stream>>>(hbuf, w2b, counts, out);
    } else {
        __bf16* hbuf = (__bf16*)d_ws;
        dim3 g1(MT_MAX, H_ / BN);
        dim3 g2(MT_MAX, D_ / BN);
        ffn_stage1<<<g1, 256, 0, stream>>>(x, w1, w3, counts, hbuf);
        ffn_stage2<<<g2, 256, 0, stream>>>(hbuf, w2, counts, out);
    }
}